// Round 3
// baseline (1498.479 us; speedup 1.0000x reference)
//
#include <hip/hip_runtime.h>
#include <hip/hip_bf16.h>

#define T_DIM 1024
#define B_DIM 4
#define E_DIM 1024
#define H_DIM 16
#define HD    64
#define M_DIM (T_DIM * B_DIM)

typedef __hip_bfloat16 bf16;

__device__ inline float toF(float x) { return x; }
__device__ inline float toF(bf16 x) { return __bfloat162float(x); }
__device__ inline void fromF(float v, float& o) { o = v; }
__device__ inline void fromF(float v, bf16& o) { o = __float2bfloat16(v); }

// C[i,j] = sum_e X[i,e] * W[j,e] + bias[j]
// X: Mdim x Kdim row-major (TX), W: Ndim x Kdim row-major (TW)
// 64x64 tile per block, 256 threads, 4x4 micro-tile, fp32 accumulate.
template <typename TX, typename TW, typename TO>
__global__ __launch_bounds__(256) void gemm_bt_bias(
    const TX* __restrict__ X, const TW* __restrict__ W,
    const float* __restrict__ bias, TO* __restrict__ C,
    int Kdim, int Ndim)
{
  const int tid = threadIdx.x;
  const int tx = tid & 15, ty = tid >> 4;
  const int bm = blockIdx.x * 64, bn = blockIdx.y * 64;
  __shared__ float Xs[16][65];
  __shared__ float Ws[16][65];
  float acc[4][4] = {};
  for (int k0 = 0; k0 < Kdim; k0 += 16) {
#pragma unroll
    for (int r = 0; r < 4; ++r) {
      int idx = tid + r * 256;          // 0..1023
      int kk = idx & 15, mm = idx >> 4; // 64 rows x 16 k
      Xs[kk][mm] = toF(X[(size_t)(bm + mm) * Kdim + k0 + kk]);
      Ws[kk][mm] = toF(W[(size_t)(bn + mm) * Kdim + k0 + kk]);
    }
    __syncthreads();
#pragma unroll
    for (int kk = 0; kk < 16; ++kk) {
      float xv[4], wv[4];
#pragma unroll
      for (int i = 0; i < 4; ++i) xv[i] = Xs[kk][ty * 4 + i];
#pragma unroll
      for (int j = 0; j < 4; ++j) wv[j] = Ws[kk][tx * 4 + j];
#pragma unroll
      for (int i = 0; i < 4; ++i)
#pragma unroll
        for (int j = 0; j < 4; ++j) acc[i][j] += xv[i] * wv[j];
    }
    __syncthreads();
  }
#pragma unroll
  for (int i = 0; i < 4; ++i) {
    int row = bm + ty * 4 + i;
#pragma unroll
    for (int j = 0; j < 4; ++j) {
      int col = bn + tx * 4 + j;
      fromF(acc[i][j] + bias[col], C[(size_t)row * Ndim + col]);
    }
  }
}

// One block per (head bh = b*H+h, q-tile of 64 rows). Flash-style over k-tiles.
// Q/K1/K2/V/AO all in (T, B, E) layout, head slice e = h*64 + d.
__global__ __launch_bounds__(256) void mgk_attn(
    const bf16* __restrict__ Q, const bf16* __restrict__ K1,
    const bf16* __restrict__ K2, const bf16* __restrict__ V,
    const float* __restrict__ pi, bf16* __restrict__ AO)
{
  const int bh = blockIdx.x;           // 0..63
  const int b = bh >> 4, h = bh & 15;
  const int qt = blockIdx.y;           // 0..15
  const int tid = threadIdx.x;
  const int tx = tid & 15, ty = tid >> 4;

  __shared__ float qs[64][65];
  __shared__ float ks[64][65];   // reused: K1-tile -> K2-tile -> V-tile
  __shared__ float ss[64][65];   // score tile (pi1*e1 + pi2*e2)
  __shared__ float qn[64], kn[64], rs[64];

  const float c1 = 0.0625f;   // scaling/2,   scaling = 64^-0.5 = 0.125
  const float c2 = 0.1875f;   // 3*scaling/2
  float p1 = fminf(fmaxf(fabsf(pi[h]), 1e-6f), 2.0f);
  float p2 = fminf(fmaxf(fabsf(pi[H_DIM + h]), 1e-6f), 2.0f);

  const size_t headoff = (size_t)h * HD;

  // load Q tile (64 x 64)
#pragma unroll
  for (int r = 0; r < 16; ++r) {
    int idx = tid + r * 256;
    int d = idx & 63, row = idx >> 6;
    int t = qt * 64 + row;
    qs[row][d] = __bfloat162float(Q[((size_t)t * B_DIM + b) * E_DIM + headoff + d]);
  }
  if (tid < 64) rs[tid] = 0.f;
  __syncthreads();
  if (tid < 64) {
    float s = 0.f;
    for (int d = 0; d < 64; ++d) { float x = qs[tid][d]; s += x * x; }
    qn[tid] = s;
  }
  __syncthreads();

  float acc[4][4] = {};
  for (int kt = 0; kt < 16; ++kt) {
    const int s0 = kt * 64;
    // ---- load K1 tile ----
#pragma unroll
    for (int r = 0; r < 16; ++r) {
      int idx = tid + r * 256;
      int d = idx & 63, row = idx >> 6;
      ks[row][d] = __bfloat162float(K1[((size_t)(s0 + row) * B_DIM + b) * E_DIM + headoff + d]);
    }
    __syncthreads();
    if (tid < 64) {
      float s = 0.f;
      for (int d = 0; d < 64; ++d) { float x = ks[tid][d]; s += x * x; }
      kn[tid] = s;
    }
    __syncthreads();
    float a[4][4];
    {
      float dot[4][4] = {};
      for (int d = 0; d < 64; ++d) {
        float qv[4], kv[4];
#pragma unroll
        for (int i = 0; i < 4; ++i) qv[i] = qs[ty * 4 + i][d];
#pragma unroll
        for (int j = 0; j < 4; ++j) kv[j] = ks[tx * 4 + j][d];
#pragma unroll
        for (int i = 0; i < 4; ++i)
#pragma unroll
          for (int j = 0; j < 4; ++j) dot[i][j] += qv[i] * kv[j];
      }
#pragma unroll
      for (int i = 0; i < 4; ++i)
#pragma unroll
        for (int j = 0; j < 4; ++j)
          a[i][j] = p1 * __expf(-c1 * (qn[ty * 4 + i] + kn[tx * 4 + j] - 2.f * dot[i][j]));
    }
    __syncthreads();  // everyone done reading K1 tile
    // ---- load K2 tile ----
#pragma unroll
    for (int r = 0; r < 16; ++r) {
      int idx = tid + r * 256;
      int d = idx & 63, row = idx >> 6;
      ks[row][d] = __bfloat162float(K2[((size_t)(s0 + row) * B_DIM + b) * E_DIM + headoff + d]);
    }
    __syncthreads();
    if (tid < 64) {
      float s = 0.f;
      for (int d = 0; d < 64; ++d) { float x = ks[tid][d]; s += x * x; }
      kn[tid] = s;
    }
    __syncthreads();
    {
      float dot[4][4] = {};
      for (int d = 0; d < 64; ++d) {
        float qv[4], kv[4];
#pragma unroll
        for (int i = 0; i < 4; ++i) qv[i] = qs[ty * 4 + i][d];
#pragma unroll
        for (int j = 0; j < 4; ++j) kv[j] = ks[tx * 4 + j][d];
#pragma unroll
        for (int i = 0; i < 4; ++i)
#pragma unroll
          for (int j = 0; j < 4; ++j) dot[i][j] += qv[i] * kv[j];
      }
#pragma unroll
      for (int i = 0; i < 4; ++i)
#pragma unroll
        for (int j = 0; j < 4; ++j)
          a[i][j] += p2 * __expf(-c2 * (qn[ty * 4 + i] + kn[tx * 4 + j] - 2.f * dot[i][j]));
    }
    // write score tile
#pragma unroll
    for (int i = 0; i < 4; ++i)
#pragma unroll
      for (int j = 0; j < 4; ++j) ss[ty * 4 + i][tx * 4 + j] = a[i][j];
    __syncthreads();  // scores visible; K2 reads done -> ks free for V
    // rowsum accumulate + V load (disjoint buffers)
    if (tid < 64) {
      float s = 0.f;
      for (int j = 0; j < 64; ++j) s += ss[tid][j];
      rs[tid] += s;
    }
#pragma unroll
    for (int r = 0; r < 16; ++r) {
      int idx = tid + r * 256;
      int d = idx & 63, row = idx >> 6;
      ks[row][d] = __bfloat162float(V[((size_t)(s0 + row) * B_DIM + b) * E_DIM + headoff + d]);
    }
    __syncthreads();
    // PV accumulate
    for (int kj = 0; kj < 64; ++kj) {
      float sv[4], vv[4];
#pragma unroll
      for (int i = 0; i < 4; ++i) sv[i] = ss[ty * 4 + i][kj];
#pragma unroll
      for (int j = 0; j < 4; ++j) vv[j] = ks[kj][tx * 4 + j];
#pragma unroll
      for (int i = 0; i < 4; ++i)
#pragma unroll
        for (int j = 0; j < 4; ++j) acc[i][j] += sv[i] * vv[j];
    }
    __syncthreads();  // before next iteration overwrites ks
  }

  // normalize + write AO in (T,B,E)
#pragma unroll
  for (int i = 0; i < 4; ++i) {
    int qi = ty * 4 + i;
    int t = qt * 64 + qi;
    float inv = 1.f / (rs[qi] + 1e-6f);
#pragma unroll
    for (int j = 0; j < 4; ++j) {
      int d = tx * 4 + j;
      AO[((size_t)t * B_DIM + b) * E_DIM + headoff + d] = __float2bfloat16(acc[i][j] * inv);
    }
  }
}

extern "C" void kernel_launch(void* const* d_in, const int* in_sizes, int n_in,
                              void* d_out, int out_size, void* d_ws, size_t ws_size,
                              hipStream_t stream) {
  const float* query = (const float*)d_in[0];
  const float* key   = (const float*)d_in[1];
  const float* value = (const float*)d_in[2];
  const float* Wq    = (const float*)d_in[3];
  const float* Wk1   = (const float*)d_in[4];
  const float* Wk2   = (const float*)d_in[5];
  const float* Wv    = (const float*)d_in[6];
  const float* bin   = (const float*)d_in[7];
  const float* Wo    = (const float*)d_in[8];
  const float* bo    = (const float*)d_in[9];
  const float* pi    = (const float*)d_in[10];
  float* out = (float*)d_out;

  const size_t NELEM = (size_t)M_DIM * E_DIM;  // 4M elements per buffer
  bf16* Qp  = (bf16*)d_ws;
  bf16* K1p = Qp + NELEM;
  bf16* K2p = K1p + NELEM;
  bf16* Vp  = K2p + NELEM;
  bf16* AO  = Vp + NELEM;

  dim3 gg(M_DIM / 64, E_DIM / 64);  // (64, 16)
  gemm_bt_bias<float, float, bf16><<<gg, 256, 0, stream>>>(query, Wq,  bin,             Qp,  E_DIM, E_DIM);
  gemm_bt_bias<float, float, bf16><<<gg, 256, 0, stream>>>(key,   Wk1, bin + E_DIM,     K1p, E_DIM, E_DIM);
  gemm_bt_bias<float, float, bf16><<<gg, 256, 0, stream>>>(key,   Wk2, bin + 2 * E_DIM, K2p, E_DIM, E_DIM);
  gemm_bt_bias<float, float, bf16><<<gg, 256, 0, stream>>>(value, Wv,  bin + 3 * E_DIM, Vp,  E_DIM, E_DIM);
  mgk_attn<<<dim3(B_DIM * H_DIM, T_DIM / 64), 256, 0, stream>>>(Qp, K1p, K2p, Vp, pi, AO);
  gemm_bt_bias<bf16, float, float><<<gg, 256, 0, stream>>>(AO, Wo, bo, out, E_DIM, E_DIM);
}

// Round 4
// 805.734 us; speedup vs baseline: 1.8598x; 1.8598x over previous
//
#include <hip/hip_runtime.h>
#include <hip/hip_bf16.h>

#define T_DIM 1024
#define B_DIM 4
#define E_DIM 1024
#define H_DIM 16
#define HD    64
#define M_DIM (T_DIM * B_DIM)   // 4096

typedef __hip_bfloat16 bf16;
typedef __bf16 bf16x8 __attribute__((ext_vector_type(8)));
typedef float  f32x4  __attribute__((ext_vector_type(4)));

// ---------------------------------------------------------------- f32 -> bf16
__global__ __launch_bounds__(256) void cvt_f32_bf16(
    const float* __restrict__ src, __bf16* __restrict__ dst, int n)
{
  int i = (blockIdx.x * 256 + threadIdx.x) * 8;
  if (i >= n) return;
  float4 a = *(const float4*)(src + i);
  float4 b = *(const float4*)(src + i + 4);
  bf16x8 o;
  o[0] = (__bf16)a.x; o[1] = (__bf16)a.y; o[2] = (__bf16)a.z; o[3] = (__bf16)a.w;
  o[4] = (__bf16)b.x; o[5] = (__bf16)b.y; o[6] = (__bf16)b.z; o[7] = (__bf16)b.w;
  *(bf16x8*)(dst + i) = o;
}

// ------------------------------------------------- async global->LDS, 16 B/lane
__device__ __forceinline__ void load_lds16(const __bf16* g, __bf16* l) {
  __builtin_amdgcn_global_load_lds(
      (__attribute__((address_space(1))) void*)(void*)g,
      (__attribute__((address_space(3))) void*)l, 16, 0, 0);
}

// ------------------------------------------------------------- MFMA GEMM (B^T)
// C[m,n] = sum_k X[m,k] * W[n,k] + bias[n]
// X: M x K row-major bf16, W: N x K row-major bf16. 128x128 tile, BK=32,
// 4 waves, each wave 64x64 (4x4 mfma_f32_16x16x32_bf16), m97 structure.
template <typename TO>
__global__ __launch_bounds__(256) void gemm_mfma_bt(
    const __bf16* __restrict__ X, const __bf16* __restrict__ W,
    const float* __restrict__ bias, TO* __restrict__ C, int Ndim, int Kdim)
{
  __shared__ __bf16 As[128 * 32];
  __shared__ __bf16 Bs[128 * 32];
  const int tid  = threadIdx.x;
  const int lane = tid & 63;
  const int wave = tid >> 6;                 // 0..3
  const int wy = (wave >> 1) * 64;           // wave row offset in tile
  const int wx = (wave & 1) * 64;            // wave col offset in tile
  const int bm = blockIdx.x * 128, bn = blockIdx.y * 128;
  const int mrow = lane & 15, quad = lane >> 4;

  // staging map: thread tid covers 16 B at LDS byte tid*16 (+ second half),
  // i.e. tile row = tid>>2, k-chunk = (tid&3)*8   (tile row-major [row][32k])
  const int srow = tid >> 2;
  const int ke   = (tid & 3) * 8;
  const __bf16* gA0 = X + (size_t)(bm + srow)      * Kdim + ke;
  const __bf16* gA1 = X + (size_t)(bm + srow + 64) * Kdim + ke;
  const __bf16* gB0 = W + (size_t)(bn + srow)      * Kdim + ke;
  const __bf16* gB1 = W + (size_t)(bn + srow + 64) * Kdim + ke;
  __bf16* lA0 = As + tid * 8;
  __bf16* lA1 = As + (tid + 256) * 8;
  __bf16* lB0 = Bs + tid * 8;
  __bf16* lB1 = Bs + (tid + 256) * 8;

  f32x4 acc[4][4];
#pragma unroll
  for (int i = 0; i < 4; ++i)
#pragma unroll
    for (int j = 0; j < 4; ++j) acc[i][j] = (f32x4)0.0f;

  for (int k0 = 0; k0 < Kdim; k0 += 32) {
    __syncthreads();                       // prior iter's LDS reads done
    load_lds16(gA0 + k0, lA0);
    load_lds16(gA1 + k0, lA1);
    load_lds16(gB0 + k0, lB0);
    load_lds16(gB1 + k0, lB1);
    __syncthreads();                       // staging drained (vmcnt(0) before barrier)
    bf16x8 af[4], bf[4];
#pragma unroll
    for (int i = 0; i < 4; ++i)
      af[i] = *(const bf16x8*)(As + (wy + i * 16 + mrow) * 32 + quad * 8);
#pragma unroll
    for (int j = 0; j < 4; ++j)
      bf[j] = *(const bf16x8*)(Bs + (wx + j * 16 + mrow) * 32 + quad * 8);
#pragma unroll
    for (int i = 0; i < 4; ++i)
#pragma unroll
      for (int j = 0; j < 4; ++j)
        acc[i][j] = __builtin_amdgcn_mfma_f32_16x16x32_bf16(af[i], bf[j], acc[i][j], 0, 0, 0);
  }

  // epilogue: C/D layout col=lane&15, row=quad*4+reg  (m89/m91-verified)
#pragma unroll
  for (int j = 0; j < 4; ++j) {
    int col = bn + wx + j * 16 + mrow;
    float bc = bias[col];
#pragma unroll
    for (int i = 0; i < 4; ++i) {
      int rbase = bm + wy + i * 16 + quad * 4;
#pragma unroll
      for (int r = 0; r < 4; ++r)
        C[(size_t)(rbase + r) * Ndim + col] = (TO)(acc[i][j][r] + bc);
    }
  }
}

// ------------------------------------------------------------------ attention
// One block per (head bh = b*H+h, q-tile of 64 rows). Flash-style over k-tiles.
// Q/K1/K2/V/AO all in (T, B, E) layout, head slice e = h*64 + d.
__global__ __launch_bounds__(256) void mgk_attn(
    const bf16* __restrict__ Q, const bf16* __restrict__ K1,
    const bf16* __restrict__ K2, const bf16* __restrict__ V,
    const float* __restrict__ pi, bf16* __restrict__ AO)
{
  const int bh = blockIdx.x;           // 0..63
  const int b = bh >> 4, h = bh & 15;
  const int qt = blockIdx.y;           // 0..15
  const int tid = threadIdx.x;
  const int tx = tid & 15, ty = tid >> 4;

  __shared__ float qs[64][65];
  __shared__ float ks[64][65];   // reused: K1-tile -> K2-tile -> V-tile
  __shared__ float ss[64][65];   // score tile (pi1*e1 + pi2*e2)
  __shared__ float qn[64], kn[64], rs[64];

  const float c1 = 0.0625f;   // scaling/2,   scaling = 64^-0.5 = 0.125
  const float c2 = 0.1875f;   // 3*scaling/2
  float p1 = fminf(fmaxf(fabsf(pi[h]), 1e-6f), 2.0f);
  float p2 = fminf(fmaxf(fabsf(pi[H_DIM + h]), 1e-6f), 2.0f);

  const size_t headoff = (size_t)h * HD;

#pragma unroll
  for (int r = 0; r < 16; ++r) {
    int idx = tid + r * 256;
    int d = idx & 63, row = idx >> 6;
    int t = qt * 64 + row;
    qs[row][d] = __bfloat162float(Q[((size_t)t * B_DIM + b) * E_DIM + headoff + d]);
  }
  if (tid < 64) rs[tid] = 0.f;
  __syncthreads();
  if (tid < 64) {
    float s = 0.f;
    for (int d = 0; d < 64; ++d) { float x = qs[tid][d]; s += x * x; }
    qn[tid] = s;
  }
  __syncthreads();

  float acc[4][4] = {};
  for (int kt = 0; kt < 16; ++kt) {
    const int s0 = kt * 64;
#pragma unroll
    for (int r = 0; r < 16; ++r) {
      int idx = tid + r * 256;
      int d = idx & 63, row = idx >> 6;
      ks[row][d] = __bfloat162float(K1[((size_t)(s0 + row) * B_DIM + b) * E_DIM + headoff + d]);
    }
    __syncthreads();
    if (tid < 64) {
      float s = 0.f;
      for (int d = 0; d < 64; ++d) { float x = ks[tid][d]; s += x * x; }
      kn[tid] = s;
    }
    __syncthreads();
    float a[4][4];
    {
      float dot[4][4] = {};
      for (int d = 0; d < 64; ++d) {
        float qv[4], kv[4];
#pragma unroll
        for (int i = 0; i < 4; ++i) qv[i] = qs[ty * 4 + i][d];
#pragma unroll
        for (int j = 0; j < 4; ++j) kv[j] = ks[tx * 4 + j][d];
#pragma unroll
        for (int i = 0; i < 4; ++i)
#pragma unroll
          for (int j = 0; j < 4; ++j) dot[i][j] += qv[i] * kv[j];
      }
#pragma unroll
      for (int i = 0; i < 4; ++i)
#pragma unroll
        for (int j = 0; j < 4; ++j)
          a[i][j] = p1 * __expf(-c1 * (qn[ty * 4 + i] + kn[tx * 4 + j] - 2.f * dot[i][j]));
    }
    __syncthreads();
#pragma unroll
    for (int r = 0; r < 16; ++r) {
      int idx = tid + r * 256;
      int d = idx & 63, row = idx >> 6;
      ks[row][d] = __bfloat162float(K2[((size_t)(s0 + row) * B_DIM + b) * E_DIM + headoff + d]);
    }
    __syncthreads();
    if (tid < 64) {
      float s = 0.f;
      for (int d = 0; d < 64; ++d) { float x = ks[tid][d]; s += x * x; }
      kn[tid] = s;
    }
    __syncthreads();
    {
      float dot[4][4] = {};
      for (int d = 0; d < 64; ++d) {
        float qv[4], kv[4];
#pragma unroll
        for (int i = 0; i < 4; ++i) qv[i] = qs[ty * 4 + i][d];
#pragma unroll
        for (int j = 0; j < 4; ++j) kv[j] = ks[tx * 4 + j][d];
#pragma unroll
        for (int i = 0; i < 4; ++i)
#pragma unroll
          for (int j = 0; j < 4; ++j) dot[i][j] += qv[i] * kv[j];
      }
#pragma unroll
      for (int i = 0; i < 4; ++i)
#pragma unroll
        for (int j = 0; j < 4; ++j)
          a[i][j] += p2 * __expf(-c2 * (qn[ty * 4 + i] + kn[tx * 4 + j] - 2.f * dot[i][j]));
    }
#pragma unroll
    for (int i = 0; i < 4; ++i)
#pragma unroll
      for (int j = 0; j < 4; ++j) ss[ty * 4 + i][tx * 4 + j] = a[i][j];
    __syncthreads();
    if (tid < 64) {
      float s = 0.f;
      for (int j = 0; j < 64; ++j) s += ss[tid][j];
      rs[tid] += s;
    }
#pragma unroll
    for (int r = 0; r < 16; ++r) {
      int idx = tid + r * 256;
      int d = idx & 63, row = idx >> 6;
      ks[row][d] = __bfloat162float(V[((size_t)(s0 + row) * B_DIM + b) * E_DIM + headoff + d]);
    }
    __syncthreads();
    for (int kj = 0; kj < 64; ++kj) {
      float sv[4], vv[4];
#pragma unroll
      for (int i = 0; i < 4; ++i) sv[i] = ss[ty * 4 + i][kj];
#pragma unroll
      for (int j = 0; j < 4; ++j) vv[j] = ks[kj][tx * 4 + j];
#pragma unroll
      for (int i = 0; i < 4; ++i)
#pragma unroll
        for (int j = 0; j < 4; ++j) acc[i][j] += sv[i] * vv[j];
    }
    __syncthreads();
  }

#pragma unroll
  for (int i = 0; i < 4; ++i) {
    int qi = ty * 4 + i;
    int t = qt * 64 + qi;
    float inv = 1.f / (rs[qi] + 1e-6f);
#pragma unroll
    for (int j = 0; j < 4; ++j) {
      int d = tx * 4 + j;
      AO[((size_t)t * B_DIM + b) * E_DIM + headoff + d] = __float2bfloat16(acc[i][j] * inv);
    }
  }
}

extern "C" void kernel_launch(void* const* d_in, const int* in_sizes, int n_in,
                              void* d_out, int out_size, void* d_ws, size_t ws_size,
                              hipStream_t stream) {
  const float* query = (const float*)d_in[0];
  const float* key   = (const float*)d_in[1];
  const float* value = (const float*)d_in[2];
  const float* Wq    = (const float*)d_in[3];
  const float* Wk1   = (const float*)d_in[4];
  const float* Wk2   = (const float*)d_in[5];
  const float* Wv    = (const float*)d_in[6];
  const float* bin   = (const float*)d_in[7];
  const float* Wo    = (const float*)d_in[8];
  const float* bo    = (const float*)d_in[9];
  const float* pi    = (const float*)d_in[10];
  float* out = (float*)d_out;

  const int P4 = M_DIM * E_DIM;   // 4M elements
  const int P1 = E_DIM * E_DIM;   // 1M elements
  __bf16* qc  = (__bf16*)d_ws;
  __bf16* kc  = qc  + P4;
  __bf16* vc  = kc  + P4;
  __bf16* wq  = vc  + P4;
  __bf16* wk1 = wq  + P1;
  __bf16* wk2 = wk1 + P1;
  __bf16* wv  = wk2 + P1;
  __bf16* wo  = wv  + P1;
  __bf16* Qp  = wo  + P1;
  __bf16* K1p = Qp  + P4;
  __bf16* K2p = K1p + P4;
  __bf16* Vp  = K2p + P4;
  __bf16* AO  = Vp  + P4;        // total 37M bf16 = 74 MB

  cvt_f32_bf16<<<P4 / 2048, 256, 0, stream>>>(query, qc, P4);
  cvt_f32_bf16<<<P4 / 2048, 256, 0, stream>>>(key,   kc, P4);
  cvt_f32_bf16<<<P4 / 2048, 256, 0, stream>>>(value, vc, P4);
  cvt_f32_bf16<<<P1 / 2048, 256, 0, stream>>>(Wq,  wq,  P1);
  cvt_f32_bf16<<<P1 / 2048, 256, 0, stream>>>(Wk1, wk1, P1);
  cvt_f32_bf16<<<P1 / 2048, 256, 0, stream>>>(Wk2, wk2, P1);
  cvt_f32_bf16<<<P1 / 2048, 256, 0, stream>>>(Wv,  wv,  P1);
  cvt_f32_bf16<<<P1 / 2048, 256, 0, stream>>>(Wo,  wo,  P1);

  dim3 gg(M_DIM / 128, E_DIM / 128);   // (32, 8)
  gemm_mfma_bt<__bf16><<<gg, 256, 0, stream>>>(qc, wq,  bin,             Qp,  E_DIM, E_DIM);
  gemm_mfma_bt<__bf16><<<gg, 256, 0, stream>>>(kc, wk1, bin + E_DIM,     K1p, E_DIM, E_DIM);
  gemm_mfma_bt<__bf16><<<gg, 256, 0, stream>>>(kc, wk2, bin + 2 * E_DIM, K2p, E_DIM, E_DIM);
  gemm_mfma_bt<__bf16><<<gg, 256, 0, stream>>>(vc, wv,  bin + 3 * E_DIM, Vp,  E_DIM, E_DIM);

  mgk_attn<<<dim3(B_DIM * H_DIM, T_DIM / 64), 256, 0, stream>>>(
      (const bf16*)Qp, (const bf16*)K1p, (const bf16*)K2p, (const bf16*)Vp, pi, (bf16*)AO);

  gemm_mfma_bt<float><<<gg, 256, 0, stream>>>(AO, wo, bo, out, E_DIM, E_DIM);
}

// Round 5
// 325.625 us; speedup vs baseline: 4.6019x; 2.4744x over previous
//
#include <hip/hip_runtime.h>
#include <hip/hip_bf16.h>

#define T_DIM 1024
#define B_DIM 4
#define E_DIM 1024
#define H_DIM 16
#define HD    64
#define M_DIM (T_DIM * B_DIM)   // 4096

typedef __hip_bfloat16 bf16;
typedef __bf16 bf16x8 __attribute__((ext_vector_type(8)));
typedef __bf16 bf16x4 __attribute__((ext_vector_type(4)));
typedef float  f32x4  __attribute__((ext_vector_type(4)));

// ---------------------------------------------------------------- f32 -> bf16
__global__ __launch_bounds__(256) void cvt_f32_bf16(
    const float* __restrict__ src, __bf16* __restrict__ dst, int n)
{
  int i = (blockIdx.x * 256 + threadIdx.x) * 8;
  if (i >= n) return;
  float4 a = *(const float4*)(src + i);
  float4 b = *(const float4*)(src + i + 4);
  bf16x8 o;
  o[0] = (__bf16)a.x; o[1] = (__bf16)a.y; o[2] = (__bf16)a.z; o[3] = (__bf16)a.w;
  o[4] = (__bf16)b.x; o[5] = (__bf16)b.y; o[6] = (__bf16)b.z; o[7] = (__bf16)b.w;
  *(bf16x8*)(dst + i) = o;
}

// ------------------------------------------------- async global->LDS, 16 B/lane
__device__ __forceinline__ void load_lds16(const __bf16* g, __bf16* l) {
  __builtin_amdgcn_global_load_lds(
      (__attribute__((address_space(1))) void*)(void*)g,
      (__attribute__((address_space(3))) void*)l, 16, 0, 0);
}

// ------------------------------------------------------------- MFMA GEMM (B^T)
// C[m,n] = sum_k X[m,k]*W[n,k] + bias[n]. 128x128 tile, BK=32, 4 waves.
template <typename TO>
__global__ __launch_bounds__(256) void gemm_mfma_bt(
    const __bf16* __restrict__ X, const __bf16* __restrict__ W,
    const float* __restrict__ bias, TO* __restrict__ C, int Ndim, int Kdim)
{
  __shared__ __bf16 As[128 * 32];
  __shared__ __bf16 Bs[128 * 32];
  const int tid  = threadIdx.x;
  const int lane = tid & 63;
  const int wave = tid >> 6;
  const int wy = (wave >> 1) * 64;
  const int wx = (wave & 1) * 64;
  const int bm = blockIdx.x * 128, bn = blockIdx.y * 128;
  const int mrow = lane & 15, quad = lane >> 4;

  const int srow = tid >> 2;
  const int ke   = (tid & 3) * 8;
  const __bf16* gA0 = X + (size_t)(bm + srow)      * Kdim + ke;
  const __bf16* gA1 = X + (size_t)(bm + srow + 64) * Kdim + ke;
  const __bf16* gB0 = W + (size_t)(bn + srow)      * Kdim + ke;
  const __bf16* gB1 = W + (size_t)(bn + srow + 64) * Kdim + ke;
  __bf16* lA0 = As + tid * 8;
  __bf16* lA1 = As + (tid + 256) * 8;
  __bf16* lB0 = Bs + tid * 8;
  __bf16* lB1 = Bs + (tid + 256) * 8;

  f32x4 acc[4][4];
#pragma unroll
  for (int i = 0; i < 4; ++i)
#pragma unroll
    for (int j = 0; j < 4; ++j) acc[i][j] = (f32x4)0.0f;

  for (int k0 = 0; k0 < Kdim; k0 += 32) {
    __syncthreads();
    load_lds16(gA0 + k0, lA0);
    load_lds16(gA1 + k0, lA1);
    load_lds16(gB0 + k0, lB0);
    load_lds16(gB1 + k0, lB1);
    __syncthreads();
    bf16x8 af[4], bf[4];
#pragma unroll
    for (int i = 0; i < 4; ++i)
      af[i] = *(const bf16x8*)(As + (wy + i * 16 + mrow) * 32 + quad * 8);
#pragma unroll
    for (int j = 0; j < 4; ++j)
      bf[j] = *(const bf16x8*)(Bs + (wx + j * 16 + mrow) * 32 + quad * 8);
#pragma unroll
    for (int i = 0; i < 4; ++i)
#pragma unroll
      for (int j = 0; j < 4; ++j)
        acc[i][j] = __builtin_amdgcn_mfma_f32_16x16x32_bf16(af[i], bf[j], acc[i][j], 0, 0, 0);
  }

#pragma unroll
  for (int j = 0; j < 4; ++j) {
    int col = bn + wx + j * 16 + mrow;
    float bc = bias[col];
#pragma unroll
    for (int i = 0; i < 4; ++i) {
      int rbase = bm + wy + i * 16 + quad * 4;
#pragma unroll
      for (int r = 0; r < 4; ++r)
        C[(size_t)(rbase + r) * Ndim + col] = (TO)(acc[i][j][r] + bc);
    }
  }
}

// ----------------------------------------------------- per-head row norms (f32)
// qn/kn1/kn2 [bh][t] = sum_d X[(t*4+b)*1024 + h*64 + d]^2
__global__ __launch_bounds__(256) void head_norms(
    const __bf16* __restrict__ Qp, const __bf16* __restrict__ K1p,
    const __bf16* __restrict__ K2p, float* __restrict__ qn,
    float* __restrict__ kn1, float* __restrict__ kn2)
{
  int id = blockIdx.x * 256 + threadIdx.x;     // 0..196607
  int which = id >> 16;
  int r = id & 65535;
  int bh = r >> 10, t = r & 1023;
  int b = bh >> 4, h = bh & 15;
  const __bf16* src = (which == 0) ? Qp : ((which == 1) ? K1p : K2p);
  float* dst = (which == 0) ? qn : ((which == 1) ? kn1 : kn2);
  const __bf16* p = src + (size_t)(t * 4 + b) * 1024 + h * 64;
  float s = 0.f;
#pragma unroll
  for (int c = 0; c < 8; ++c) {
    bf16x8 v = *(const bf16x8*)(p + c * 8);
#pragma unroll
    for (int j = 0; j < 8; ++j) { float x = (float)v[j]; s += x * x; }
  }
  dst[bh * 1024 + t] = s;
}

// -------------------------------------------------------- MFMA flash attention
// block = (bh, qt): 128 q-rows; 4 waves x 32 q-rows. 64-key tiles.
// All LDS tiles 64-col rows with XOR chunk swizzle: phys_chunk = lc ^ (row&7).
// Key permutation sigma(u) = (u&3)*16 + (u>>2) applied to Pl and Vt key axes.
__global__ __launch_bounds__(256, 2) void mgk_attn_mfma(
    const __bf16* __restrict__ Qp, const __bf16* __restrict__ K1p,
    const __bf16* __restrict__ K2p, const __bf16* __restrict__ Vp,
    const float* __restrict__ qn_g, const float* __restrict__ kn1_g,
    const float* __restrict__ kn2_g, const float* __restrict__ pi,
    __bf16* __restrict__ AO)
{
  __shared__ __bf16 lds[28672];          // 56 KB
  __bf16* Qs  = lds;                     // 128x64
  __bf16* K1s = lds + 8192;              // 64x64
  __bf16* K2s = lds + 12288;             // 64x64
  __bf16* Vt  = lds + 16384;             // 64(d) x 64(u)
  __bf16* Pl  = lds + 20480;             // 4 waves x 32(q) x 64(u)

  const int bh = blockIdx.x, qt = blockIdx.y;
  const int b = bh >> 4, h = bh & 15;
  const int tid = threadIdx.x, lane = tid & 63, w = tid >> 6;
  const int mrow = lane & 15, quad = lane >> 4;

  const float c1 = 0.0625f;    // scaling/2
  const float c2 = 0.1875f;    // 3*scaling/2
  const float p1 = fminf(fmaxf(fabsf(pi[h]), 1e-6f), 2.0f);
  const float p2 = fminf(fmaxf(fabsf(pi[H_DIM + h]), 1e-6f), 2.0f);
  const int hoff = h * 64;

  // qn vector per lane: rows i*16 + quad*4 + r (within wave's 32 q)
  f32x4 qnv[2];
#pragma unroll
  for (int i = 0; i < 2; ++i)
    qnv[i] = *(const f32x4*)(qn_g + bh * 1024 + qt * 128 + w * 32 + i * 16 + quad * 4);

  // stage Q once (swizzled via source-chunk permutation)
#pragma unroll
  for (int wi = 0; wi < 4; ++wi) {
    int window = w * 4 + wi;
    int qr = window * 8 + (lane >> 3), c = lane & 7;
    const __bf16* src = Qp + (size_t)((qt * 128 + qr) * 4 + b) * 1024 + hoff
                        + ((c ^ (qr & 7)) << 3);
    load_lds16(src, Qs + window * 512 + lane * 8);
  }

  f32x4 oacc[2][4];
#pragma unroll
  for (int i = 0; i < 2; ++i)
#pragma unroll
    for (int j = 0; j < 4; ++j) oacc[i][j] = (f32x4)0.0f;
  f32x4 rsl[2] = {(f32x4)0.0f, (f32x4)0.0f};

  for (int kt = 0; kt < 16; ++kt) {
    __syncthreads();                               // A: prev PV reads done (+Q on iter 0)
    // stage K1,K2 (async, swizzled)
#pragma unroll
    for (int wi = 0; wi < 2; ++wi) {
      int window = w * 2 + wi;
      int kr = window * 8 + (lane >> 3), c = lane & 7;
      size_t srow = (size_t)((kt * 64 + kr) * 4 + b) * 1024 + hoff;
      int off = (c ^ (kr & 7)) << 3;
      load_lds16(K1p + srow + off, K1s + window * 512 + lane * 8);
      load_lds16(K2p + srow + off, K2s + window * 512 + lane * 8);
    }
    // stage Vt (VGPR transpose, sigma^-1 on key axis, swizzled)
    {
      int s = tid >> 2, d0 = (tid & 3) * 16;
      const __bf16* vs = Vp + (size_t)((kt * 64 + s) * 4 + b) * 1024 + hoff + d0;
      bf16x8 v0 = *(const bf16x8*)(vs);
      bf16x8 v1 = *(const bf16x8*)(vs + 8);
      int u = ((s & 15) << 2) + (s >> 4);          // sigma^-1(s)
      int ulo = u & 7, uch = u >> 3;
#pragma unroll
      for (int r2 = 0; r2 < 8; ++r2) {
        int d = d0 + r2;
        Vt[d * 64 + ((uch ^ (d & 7)) << 3) + ulo] = v0[r2];
        int d2 = d0 + 8 + r2;
        Vt[d2 * 64 + ((uch ^ (d2 & 7)) << 3) + ulo] = v1[r2];
      }
    }
    // key norms for this tile
    float kn1j[4], kn2j[4];
#pragma unroll
    for (int j = 0; j < 4; ++j) {
      kn1j[j] = kn1_g[bh * 1024 + kt * 64 + j * 16 + mrow];
      kn2j[j] = kn2_g[bh * 1024 + kt * 64 + j * 16 + mrow];
    }
    __syncthreads();                               // B: K1s/K2s/Vt ready

    // ---- S1, S2 via MFMA ----
    bf16x8 af[2][2];
#pragma unroll
    for (int i = 0; i < 2; ++i)
#pragma unroll
      for (int kk = 0; kk < 2; ++kk)
        af[i][kk] = *(const bf16x8*)(Qs + (w * 32 + i * 16 + mrow) * 64
                                     + (((kk * 4 + quad) ^ (mrow & 7)) << 3));
    f32x4 acc1[2][4], acc2[2][4];
#pragma unroll
    for (int i = 0; i < 2; ++i)
#pragma unroll
      for (int j = 0; j < 4; ++j) { acc1[i][j] = (f32x4)0.0f; acc2[i][j] = (f32x4)0.0f; }
#pragma unroll
    for (int kk = 0; kk < 2; ++kk)
#pragma unroll
      for (int j = 0; j < 4; ++j) {
        bf16x8 b1f = *(const bf16x8*)(K1s + (j * 16 + mrow) * 64
                                      + (((kk * 4 + quad) ^ (mrow & 7)) << 3));
        bf16x8 b2f = *(const bf16x8*)(K2s + (j * 16 + mrow) * 64
                                      + (((kk * 4 + quad) ^ (mrow & 7)) << 3));
#pragma unroll
        for (int i = 0; i < 2; ++i) {
          acc1[i][j] = __builtin_amdgcn_mfma_f32_16x16x32_bf16(af[i][kk], b1f, acc1[i][j], 0, 0, 0);
          acc2[i][j] = __builtin_amdgcn_mfma_f32_16x16x32_bf16(af[i][kk], b2f, acc2[i][j], 0, 0, 0);
        }
      }

    // ---- P = p1*exp(-c1*sqd1) + p2*exp(-c2*sqd2); write to Pl (sigma order) ----
#pragma unroll
    for (int i = 0; i < 2; ++i) {
      f32x4 pv[4];
#pragma unroll
      for (int j = 0; j < 4; ++j) {
        f32x4 p;
#pragma unroll
        for (int r = 0; r < 4; ++r) {
          float arg1 = c1 * (2.0f * acc1[i][j][r] - qnv[i][r] - kn1j[j]);
          float arg2 = c2 * (2.0f * acc2[i][j][r] - qnv[i][r] - kn2j[j]);
          p[r] = p1 * __expf(arg1) + p2 * __expf(arg2);
        }
        pv[j] = p;
        rsl[i] += p;
      }
#pragma unroll
      for (int r = 0; r < 4; ++r) {
        int q = i * 16 + quad * 4 + r;             // wave-local row
        bf16x4 pk;
        pk[0] = (__bf16)pv[0][r]; pk[1] = (__bf16)pv[1][r];
        pk[2] = (__bf16)pv[2][r]; pk[3] = (__bf16)pv[3][r];
        int lc = mrow >> 1;
        *(bf16x4*)(Pl + w * 2048 + q * 64 + ((lc ^ (q & 7)) << 3) + (mrow & 1) * 4) = pk;
      }
    }
    __syncthreads();                               // C: Pl ready

    // ---- O += P * V ----
    bf16x8 pf[2][2];
#pragma unroll
    for (int i = 0; i < 2; ++i)
#pragma unroll
      for (int kk = 0; kk < 2; ++kk)
        pf[i][kk] = *(const bf16x8*)(Pl + w * 2048 + (i * 16 + mrow) * 64
                                     + (((kk * 4 + quad) ^ (mrow & 7)) << 3));
#pragma unroll
    for (int kk = 0; kk < 2; ++kk)
#pragma unroll
      for (int j = 0; j < 4; ++j) {
        bf16x8 vf = *(const bf16x8*)(Vt + (j * 16 + mrow) * 64
                                     + (((kk * 4 + quad) ^ (mrow & 7)) << 3));
#pragma unroll
        for (int i = 0; i < 2; ++i)
          oacc[i][j] = __builtin_amdgcn_mfma_f32_16x16x32_bf16(pf[i][kk], vf, oacc[i][j], 0, 0, 0);
      }
  }

  // rowsum butterfly across 16 lanes (mrow) within each quad group
#pragma unroll
  for (int i = 0; i < 2; ++i)
#pragma unroll
    for (int d = 1; d < 16; d <<= 1) {
      f32x4 o;
#pragma unroll
      for (int r = 0; r < 4; ++r) o[r] = __shfl_xor(rsl[i][r], d, 64);
      rsl[i] += o;
    }

  // normalize + write AO (M,E) bf16
#pragma unroll
  for (int i = 0; i < 2; ++i) {
    f32x4 inv;
#pragma unroll
    for (int r = 0; r < 4; ++r) inv[r] = 1.0f / (rsl[i][r] + 1e-6f);
#pragma unroll
    for (int j = 0; j < 4; ++j) {
      int col = hoff + j * 16 + mrow;
#pragma unroll
      for (int r = 0; r < 4; ++r) {
        int t = qt * 128 + w * 32 + i * 16 + quad * 4 + r;
        AO[(size_t)(t * 4 + b) * 1024 + col] = (__bf16)(oacc[i][j][r] * inv[r]);
      }
    }
  }
}

extern "C" void kernel_launch(void* const* d_in, const int* in_sizes, int n_in,
                              void* d_out, int out_size, void* d_ws, size_t ws_size,
                              hipStream_t stream) {
  const float* query = (const float*)d_in[0];
  const float* key   = (const float*)d_in[1];
  const float* value = (const float*)d_in[2];
  const float* Wq    = (const float*)d_in[3];
  const float* Wk1   = (const float*)d_in[4];
  const float* Wk2   = (const float*)d_in[5];
  const float* Wv    = (const float*)d_in[6];
  const float* bin   = (const float*)d_in[7];
  const float* Wo    = (const float*)d_in[8];
  const float* bo    = (const float*)d_in[9];
  const float* pi    = (const float*)d_in[10];
  float* out = (float*)d_out;

  const int P4 = M_DIM * E_DIM;   // 4M elements
  const int P1 = E_DIM * E_DIM;   // 1M elements
  __bf16* qc  = (__bf16*)d_ws;
  __bf16* kc  = qc  + P4;
  __bf16* vc  = kc  + P4;
  __bf16* wq  = vc  + P4;
  __bf16* wk1 = wq  + P1;
  __bf16* wk2 = wk1 + P1;
  __bf16* wv  = wk2 + P1;
  __bf16* wo  = wv  + P1;
  __bf16* Qp  = wo  + P1;
  __bf16* K1p = Qp  + P4;
  __bf16* K2p = K1p + P4;
  __bf16* Vp  = K2p + P4;
  __bf16* AO  = Vp  + P4;
  float*  qn_g  = (float*)(AO + P4);
  float*  kn1_g = qn_g  + 64 * 1024;
  float*  kn2_g = kn1_g + 64 * 1024;   // total ~75 MB

  cvt_f32_bf16<<<P4 / 2048, 256, 0, stream>>>(query, qc, P4);
  cvt_f32_bf16<<<P4 / 2048, 256, 0, stream>>>(key,   kc, P4);
  cvt_f32_bf16<<<P4 / 2048, 256, 0, stream>>>(value, vc, P4);
  cvt_f32_bf16<<<P1 / 2048, 256, 0, stream>>>(Wq,  wq,  P1);
  cvt_f32_bf16<<<P1 / 2048, 256, 0, stream>>>(Wk1, wk1, P1);
  cvt_f32_bf16<<<P1 / 2048, 256, 0, stream>>>(Wk2, wk2, P1);
  cvt_f32_bf16<<<P1 / 2048, 256, 0, stream>>>(Wv,  wv,  P1);
  cvt_f32_bf16<<<P1 / 2048, 256, 0, stream>>>(Wo,  wo,  P1);

  dim3 gg(M_DIM / 128, E_DIM / 128);   // (32, 8)
  gemm_mfma_bt<__bf16><<<gg, 256, 0, stream>>>(qc, wq,  bin,             Qp,  E_DIM, E_DIM);
  gemm_mfma_bt<__bf16><<<gg, 256, 0, stream>>>(kc, wk1, bin + E_DIM,     K1p, E_DIM, E_DIM);
  gemm_mfma_bt<__bf16><<<gg, 256, 0, stream>>>(kc, wk2, bin + 2 * E_DIM, K2p, E_DIM, E_DIM);
  gemm_mfma_bt<__bf16><<<gg, 256, 0, stream>>>(vc, wv,  bin + 3 * E_DIM, Vp,  E_DIM, E_DIM);

  head_norms<<<768, 256, 0, stream>>>(Qp, K1p, K2p, qn_g, kn1_g, kn2_g);

  mgk_attn_mfma<<<dim3(64, 8), 256, 0, stream>>>(
      Qp, K1p, K2p, Vp, qn_g, kn1_g, kn2_g, pi, AO);

  gemm_mfma_bt<float><<<gg, 256, 0, stream>>>(AO, wo, bo, out, E_DIM, E_DIM);
}

// Round 6
// 279.198 us; speedup vs baseline: 5.3671x; 1.1663x over previous
//
#include <hip/hip_runtime.h>
#include <hip/hip_bf16.h>

#define T_DIM 1024
#define B_DIM 4
#define E_DIM 1024
#define H_DIM 16
#define HD    64
#define M_DIM (T_DIM * B_DIM)   // 4096

typedef __hip_bfloat16 bf16;
typedef __bf16 bf16x8 __attribute__((ext_vector_type(8)));
typedef __bf16 bf16x4 __attribute__((ext_vector_type(4)));
typedef float  f32x4  __attribute__((ext_vector_type(4)));

#define P4S ((size_t)M_DIM * E_DIM)   // 4194304
#define P1S ((size_t)E_DIM * E_DIM)   // 1048576

// ------------------------------------------- fused f32 -> bf16 (all 8 buffers)
// dst region is qc|kc|vc|wq|wk1|wk2|wv|wo contiguous (3*P4 + 5*P1 elems).
__global__ __launch_bounds__(256) void cvt_all(
    const float* __restrict__ q, const float* __restrict__ k,
    const float* __restrict__ v, const float* __restrict__ w0,
    const float* __restrict__ w1, const float* __restrict__ w2,
    const float* __restrict__ w3, const float* __restrict__ w4,
    __bf16* __restrict__ dst)
{
  size_t i = ((size_t)blockIdx.x * 256 + threadIdx.x) * 8;
  const float* src;
  size_t off;
  if (i < P4S)            { src = q; off = i; }
  else if (i < 2 * P4S)   { src = k; off = i - P4S; }
  else if (i < 3 * P4S)   { src = v; off = i - 2 * P4S; }
  else {
    size_t j = i - 3 * P4S;
    int wsel = (int)(j >> 20);          // /P1S
    off = j & (P1S - 1);
    const float* ws[5] = {w0, w1, w2, w3, w4};
    src = ws[wsel];
  }
  float4 a = *(const float4*)(src + off);
  float4 b = *(const float4*)(src + off + 4);
  bf16x8 o;
  o[0] = (__bf16)a.x; o[1] = (__bf16)a.y; o[2] = (__bf16)a.z; o[3] = (__bf16)a.w;
  o[4] = (__bf16)b.x; o[5] = (__bf16)b.y; o[6] = (__bf16)b.z; o[7] = (__bf16)b.w;
  *(bf16x8*)(dst + i) = o;
}

// ------------------------------------------------- async global->LDS, 16 B/lane
__device__ __forceinline__ void load_lds16(const __bf16* g, __bf16* l) {
  __builtin_amdgcn_global_load_lds(
      (__attribute__((address_space(1))) void*)(void*)g,
      (__attribute__((address_space(3))) void*)l, 16, 0, 0);
}

// --------------------------------------------------- GEMM core (128x128, BK=32)
template <typename TO>
__device__ __forceinline__ void gemm_body(
    const __bf16* __restrict__ X, const __bf16* __restrict__ W,
    const float* __restrict__ bias, TO* __restrict__ C,
    int bm, int bn, int Ndim, int Kdim, __bf16* As, __bf16* Bs)
{
  const int tid  = threadIdx.x;
  const int lane = tid & 63;
  const int wave = tid >> 6;
  const int wy = (wave >> 1) * 64;
  const int wx = (wave & 1) * 64;
  const int mrow = lane & 15, quad = lane >> 4;

  const int srow = tid >> 2;
  const int ke   = (tid & 3) * 8;
  const __bf16* gA0 = X + (size_t)(bm + srow)      * Kdim + ke;
  const __bf16* gA1 = X + (size_t)(bm + srow + 64) * Kdim + ke;
  const __bf16* gB0 = W + (size_t)(bn + srow)      * Kdim + ke;
  const __bf16* gB1 = W + (size_t)(bn + srow + 64) * Kdim + ke;
  __bf16* lA0 = As + tid * 8;
  __bf16* lA1 = As + (tid + 256) * 8;
  __bf16* lB0 = Bs + tid * 8;
  __bf16* lB1 = Bs + (tid + 256) * 8;

  f32x4 acc[4][4];
#pragma unroll
  for (int i = 0; i < 4; ++i)
#pragma unroll
    for (int j = 0; j < 4; ++j) acc[i][j] = (f32x4)0.0f;

  for (int k0 = 0; k0 < Kdim; k0 += 32) {
    __syncthreads();
    load_lds16(gA0 + k0, lA0);
    load_lds16(gA1 + k0, lA1);
    load_lds16(gB0 + k0, lB0);
    load_lds16(gB1 + k0, lB1);
    __syncthreads();
    bf16x8 af[4], bf[4];
#pragma unroll
    for (int i = 0; i < 4; ++i)
      af[i] = *(const bf16x8*)(As + (wy + i * 16 + mrow) * 32 + quad * 8);
#pragma unroll
    for (int j = 0; j < 4; ++j)
      bf[j] = *(const bf16x8*)(Bs + (wx + j * 16 + mrow) * 32 + quad * 8);
#pragma unroll
    for (int i = 0; i < 4; ++i)
#pragma unroll
      for (int j = 0; j < 4; ++j)
        acc[i][j] = __builtin_amdgcn_mfma_f32_16x16x32_bf16(af[i], bf[j], acc[i][j], 0, 0, 0);
  }

#pragma unroll
  for (int j = 0; j < 4; ++j) {
    int col = bn + wx + j * 16 + mrow;
    float bc = bias[col];
#pragma unroll
    for (int i = 0; i < 4; ++i) {
      int rbase = bm + wy + i * 16 + quad * 4;
#pragma unroll
      for (int r = 0; r < 4; ++r)
        C[(size_t)(rbase + r) * Ndim + col] = (TO)(acc[i][j][r] + bc);
    }
  }
}

// All four projection GEMMs in one dispatch; z picks {q,k1,k2,v}.
// xbase = qc (qc|kc|vc contiguous), wbase = wq (wq..wv contiguous),
// cbase = Qp (Qp|K1p|K2p|Vp contiguous), bias = bin + z*1024.
__global__ __launch_bounds__(256) void proj_gemm4(
    const __bf16* __restrict__ xbase, const __bf16* __restrict__ wbase,
    const float* __restrict__ bin, __bf16* __restrict__ cbase)
{
  __shared__ __bf16 As[128 * 32];
  __shared__ __bf16 Bs[128 * 32];
  const int z = blockIdx.z;
  const __bf16* X = xbase + ((z == 0) ? 0 : (z == 3) ? 2 * P4S : P4S);
  const __bf16* W = wbase + (size_t)z * P1S;
  const float* bias = bin + z * E_DIM;
  __bf16* C = cbase + (size_t)z * P4S;
  gemm_body<__bf16>(X, W, bias, C, blockIdx.x * 128, blockIdx.y * 128,
                    E_DIM, E_DIM, As, Bs);
}

// Output projection (f32 out).
__global__ __launch_bounds__(256) void out_gemm(
    const __bf16* __restrict__ X, const __bf16* __restrict__ W,
    const float* __restrict__ bias, float* __restrict__ C)
{
  __shared__ __bf16 As[128 * 32];
  __shared__ __bf16 Bs[128 * 32];
  gemm_body<float>(X, W, bias, C, blockIdx.x * 128, blockIdx.y * 128,
                   E_DIM, E_DIM, As, Bs);
}

// ----------------------------------------------------- per-head row norms (f32)
__global__ __launch_bounds__(256) void head_norms(
    const __bf16* __restrict__ Qp, const __bf16* __restrict__ K1p,
    const __bf16* __restrict__ K2p, float* __restrict__ qn,
    float* __restrict__ kn1, float* __restrict__ kn2)
{
  int id = blockIdx.x * 256 + threadIdx.x;     // 0..196607
  int which = id >> 16;
  int r = id & 65535;
  int bh = r >> 10, t = r & 1023;
  int b = bh >> 4, h = bh & 15;
  const __bf16* src = (which == 0) ? Qp : ((which == 1) ? K1p : K2p);
  float* dst = (which == 0) ? qn : ((which == 1) ? kn1 : kn2);
  const __bf16* p = src + (size_t)(t * 4 + b) * 1024 + h * 64;
  float s = 0.f;
#pragma unroll
  for (int c = 0; c < 8; ++c) {
    bf16x8 v = *(const bf16x8*)(p + c * 8);
#pragma unroll
    for (int j = 0; j < 8; ++j) { float x = (float)v[j]; s += x * x; }
  }
  dst[bh * 1024 + t] = s;
}

// -------------------------------------- V transpose: Vp(T,B,E) -> Vt_g[bh][d][u]
// u within each 64-key tile is sigma-permuted: Vt_g[bh][d][kt*64+u] = V[kt*64+sigma(u)][d],
// sigma(u) = (u&3)*16 + (u>>2).
__global__ __launch_bounds__(256) void v_transpose(
    const __bf16* __restrict__ Vp, __bf16* __restrict__ Vt_g)
{
  const int bh = blockIdx.x, kt = blockIdx.y;
  const int b = bh >> 4, h = bh & 15;
  const int tid = threadIdx.x;
  __shared__ __bf16 tile[64][88];   // 176 B rows: 16B-aligned, conflict-mild
  {
    int s = tid >> 2, d0 = (tid & 3) * 16;
    const __bf16* src = Vp + (size_t)((kt * 64 + s) * 4 + b) * 1024 + h * 64 + d0;
    *(bf16x8*)(&tile[s][d0])     = *(const bf16x8*)(src);
    *(bf16x8*)(&tile[s][d0 + 8]) = *(const bf16x8*)(src + 8);
  }
  __syncthreads();
#pragma unroll
  for (int c = 0; c < 2; ++c) {
    int idx = tid * 2 + c;
    int d = idx >> 3, u0 = (idx & 7) * 8;
    bf16x8 o;
#pragma unroll
    for (int i = 0; i < 8; ++i) {
      int u = u0 + i;
      int s = (u & 3) * 16 + (u >> 2);
      o[i] = tile[s][d];
    }
    *(bf16x8*)(Vt_g + ((size_t)bh * 64 + d) * 1024 + kt * 64 + u0) = o;
  }
}

// -------------------------------------------------------- MFMA flash attention
// block = (bh, qt): 128 q-rows; 4 waves x 32 q-rows. 64-key tiles.
// LDS tiles: 64-col rows, XOR chunk swizzle phys_chunk = lc ^ (row&7).
// Key axis of Pl and Vt both sigma-permuted (consistent; sum order-invariant).
__global__ __launch_bounds__(256, 2) void mgk_attn_mfma(
    const __bf16* __restrict__ Qp, const __bf16* __restrict__ K1p,
    const __bf16* __restrict__ K2p, const __bf16* __restrict__ Vt_g,
    const float* __restrict__ qn_g, const float* __restrict__ kn1_g,
    const float* __restrict__ kn2_g, const float* __restrict__ pi,
    __bf16* __restrict__ AO)
{
  __shared__ __bf16 lds[28672];          // 56 KB
  __bf16* Qs  = lds;                     // 128x64
  __bf16* K1s = lds + 8192;              // 64x64
  __bf16* K2s = lds + 12288;             // 64x64
  __bf16* Vt  = lds + 16384;             // 64(d) x 64(u)
  __bf16* Pl  = lds + 20480;             // 4 waves x 32(q) x 64(u)

  const int bh = blockIdx.x, qt = blockIdx.y;
  const int b = bh >> 4, h = bh & 15;
  const int tid = threadIdx.x, lane = tid & 63, w = tid >> 6;
  const int mrow = lane & 15, quad = lane >> 4;

  const float c1 = 0.0625f;    // scaling/2
  const float c2 = 0.1875f;    // 3*scaling/2
  const float p1 = fminf(fmaxf(fabsf(pi[h]), 1e-6f), 2.0f);
  const float p2 = fminf(fmaxf(fabsf(pi[H_DIM + h]), 1e-6f), 2.0f);
  const int hoff = h * 64;

  f32x4 qnv[2];
#pragma unroll
  for (int i = 0; i < 2; ++i)
    qnv[i] = *(const f32x4*)(qn_g + bh * 1024 + qt * 128 + w * 32 + i * 16 + quad * 4);

  // stage Q once (swizzled via source-chunk permutation)
#pragma unroll
  for (int wi = 0; wi < 4; ++wi) {
    int window = w * 4 + wi;
    int qr = window * 8 + (lane >> 3), c = lane & 7;
    const __bf16* src = Qp + (size_t)((qt * 128 + qr) * 4 + b) * 1024 + hoff
                        + ((c ^ (qr & 7)) << 3);
    load_lds16(src, Qs + window * 512 + lane * 8);
  }

  f32x4 oacc[2][4];
#pragma unroll
  for (int i = 0; i < 2; ++i)
#pragma unroll
    for (int j = 0; j < 4; ++j) oacc[i][j] = (f32x4)0.0f;
  f32x4 rsl[2] = {(f32x4)0.0f, (f32x4)0.0f};

  for (int kt = 0; kt < 16; ++kt) {
    __syncthreads();                               // A: prev PV reads done (+Q on iter 0)
    // stage K1,K2,Vt (all async, swizzled)
#pragma unroll
    for (int wi = 0; wi < 2; ++wi) {
      int window = w * 2 + wi;
      int kr = window * 8 + (lane >> 3), c = lane & 7;
      size_t srow = (size_t)((kt * 64 + kr) * 4 + b) * 1024 + hoff;
      int off = (c ^ (kr & 7)) << 3;
      load_lds16(K1p + srow + off, K1s + window * 512 + lane * 8);
      load_lds16(K2p + srow + off, K2s + window * 512 + lane * 8);
      load_lds16(Vt_g + ((size_t)bh * 64 + kr) * 1024 + kt * 64 + off,
                 Vt + window * 512 + lane * 8);
    }
    // key norms for this tile
    float kn1j[4], kn2j[4];
#pragma unroll
    for (int j = 0; j < 4; ++j) {
      kn1j[j] = kn1_g[bh * 1024 + kt * 64 + j * 16 + mrow];
      kn2j[j] = kn2_g[bh * 1024 + kt * 64 + j * 16 + mrow];
    }
    __syncthreads();                               // B: K1s/K2s/Vt ready

    // ---- S1, S2 via MFMA ----
    bf16x8 af[2][2];
#pragma unroll
    for (int i = 0; i < 2; ++i)
#pragma unroll
      for (int kk = 0; kk < 2; ++kk)
        af[i][kk] = *(const bf16x8*)(Qs + (w * 32 + i * 16 + mrow) * 64
                                     + (((kk * 4 + quad) ^ (mrow & 7)) << 3));
    f32x4 acc1[2][4], acc2[2][4];
#pragma unroll
    for (int i = 0; i < 2; ++i)
#pragma unroll
      for (int j = 0; j < 4; ++j) { acc1[i][j] = (f32x4)0.0f; acc2[i][j] = (f32x4)0.0f; }
#pragma unroll
    for (int kk = 0; kk < 2; ++kk)
#pragma unroll
      for (int j = 0; j < 4; ++j) {
        bf16x8 b1f = *(const bf16x8*)(K1s + (j * 16 + mrow) * 64
                                      + (((kk * 4 + quad) ^ (mrow & 7)) << 3));
        bf16x8 b2f = *(const bf16x8*)(K2s + (j * 16 + mrow) * 64
                                      + (((kk * 4 + quad) ^ (mrow & 7)) << 3));
#pragma unroll
        for (int i = 0; i < 2; ++i) {
          acc1[i][j] = __builtin_amdgcn_mfma_f32_16x16x32_bf16(af[i][kk], b1f, acc1[i][j], 0, 0, 0);
          acc2[i][j] = __builtin_amdgcn_mfma_f32_16x16x32_bf16(af[i][kk], b2f, acc2[i][j], 0, 0, 0);
        }
      }

    // ---- P = p1*exp(-c1*sqd1) + p2*exp(-c2*sqd2); write to Pl (sigma order) ----
#pragma unroll
    for (int i = 0; i < 2; ++i) {
      f32x4 pv[4];
#pragma unroll
      for (int j = 0; j < 4; ++j) {
        f32x4 p;
#pragma unroll
        for (int r = 0; r < 4; ++r) {
          float arg1 = c1 * (2.0f * acc1[i][j][r] - qnv[i][r] - kn1j[j]);
          float arg2 = c2 * (2.0f * acc2[i][j][r] - qnv[i][r] - kn2j[j]);
          p[r] = p1 * __expf(arg1) + p2 * __expf(arg2);
        }
        pv[j] = p;
        rsl[i] += p;
      }
#pragma unroll
      for (int r = 0; r < 4; ++r) {
        int q = i * 16 + quad * 4 + r;             // wave-local row
        bf16x4 pk;
        pk[0] = (__bf16)pv[0][r]; pk[1] = (__bf16)pv[1][r];
        pk[2] = (__bf16)pv[2][r]; pk[3] = (__bf16)pv[3][r];
        int lc = mrow >> 1;
        *(bf16x4*)(Pl + w * 2048 + q * 64 + ((lc ^ (q & 7)) << 3) + (mrow & 1) * 4) = pk;
      }
    }
    __syncthreads();                               // C: Pl ready

    // ---- O += P * V ----
    bf16x8 pf[2][2];
#pragma unroll
    for (int i = 0; i < 2; ++i)
#pragma unroll
      for (int kk = 0; kk < 2; ++kk)
        pf[i][kk] = *(const bf16x8*)(Pl + w * 2048 + (i * 16 + mrow) * 64
                                     + (((kk * 4 + quad) ^ (mrow & 7)) << 3));
#pragma unroll
    for (int kk = 0; kk < 2; ++kk)
#pragma unroll
      for (int j = 0; j < 4; ++j) {
        bf16x8 vf = *(const bf16x8*)(Vt + (j * 16 + mrow) * 64
                                     + (((kk * 4 + quad) ^ (mrow & 7)) << 3));
#pragma unroll
        for (int i = 0; i < 2; ++i)
          oacc[i][j] = __builtin_amdgcn_mfma_f32_16x16x32_bf16(pf[i][kk], vf, oacc[i][j], 0, 0, 0);
      }
  }

  // rowsum butterfly across 16 lanes (mrow)
#pragma unroll
  for (int i = 0; i < 2; ++i)
#pragma unroll
    for (int d = 1; d < 16; d <<= 1) {
      f32x4 o;
#pragma unroll
      for (int r = 0; r < 4; ++r) o[r] = __shfl_xor(rsl[i][r], d, 64);
      rsl[i] += o;
    }

  // normalize + write AO (M,E) bf16
#pragma unroll
  for (int i = 0; i < 2; ++i) {
    f32x4 inv;
#pragma unroll
    for (int r = 0; r < 4; ++r) inv[r] = 1.0f / (rsl[i][r] + 1e-6f);
#pragma unroll
    for (int j = 0; j < 4; ++j) {
      int col = hoff + j * 16 + mrow;
#pragma unroll
      for (int r = 0; r < 4; ++r) {
        int t = qt * 128 + w * 32 + i * 16 + quad * 4 + r;
        AO[(size_t)(t * 4 + b) * 1024 + col] = (__bf16)(oacc[i][j][r] * inv[r]);
      }
    }
  }
}

extern "C" void kernel_launch(void* const* d_in, const int* in_sizes, int n_in,
                              void* d_out, int out_size, void* d_ws, size_t ws_size,
                              hipStream_t stream) {
  const float* query = (const float*)d_in[0];
  const float* key   = (const float*)d_in[1];
  const float* value = (const float*)d_in[2];
  const float* Wq    = (const float*)d_in[3];
  const float* Wk1   = (const float*)d_in[4];
  const float* Wk2   = (const float*)d_in[5];
  const float* Wv    = (const float*)d_in[6];
  const float* bin   = (const float*)d_in[7];
  const float* Wo    = (const float*)d_in[8];
  const float* bo    = (const float*)d_in[9];
  const float* pi    = (const float*)d_in[10];
  float* out = (float*)d_out;

  __bf16* qc  = (__bf16*)d_ws;          // 3*P4: qc|kc|vc
  __bf16* wq  = qc  + 3 * P4S;          // 5*P1: wq|wk1|wk2|wv|wo
  __bf16* wo  = wq  + 4 * P1S;
  __bf16* Qp  = wq  + 5 * P1S;          // 4*P4: Qp|K1p|K2p|Vp
  __bf16* K1p = Qp  + P4S;
  __bf16* K2p = K1p + P4S;
  __bf16* Vp  = K2p + P4S;
  __bf16* AO  = Vp  + P4S;
  float*  qn_g  = (float*)(AO + P4S);
  float*  kn1_g = qn_g  + 64 * 1024;
  float*  kn2_g = kn1_g + 64 * 1024;
  __bf16* Vt_g  = qc;                   // reuse: qc dead after proj_gemm4

  // 1 conversion dispatch: 3*P4 + 5*P1 = 17825792 elems / 8 per thread
  cvt_all<<<8704, 256, 0, stream>>>(query, key, value, Wq, Wk1, Wk2, Wv, Wo, qc);

  // 4 projections in one dispatch (1024 blocks)
  proj_gemm4<<<dim3(M_DIM / 128, E_DIM / 128, 4), 256, 0, stream>>>(qc, wq, bin, Qp);

  head_norms<<<768, 256, 0, stream>>>(Qp, K1p, K2p, qn_g, kn1_g, kn2_g);
  v_transpose<<<dim3(64, 16), 256, 0, stream>>>(Vp, Vt_g);

  mgk_attn_mfma<<<dim3(64, 8), 256, 0, stream>>>(
      Qp, K1p, K2p, Vt_g, qn_g, kn1_g, kn2_g, pi, AO);

  out_gemm<<<dim3(M_DIM / 128, E_DIM / 128), 256, 0, stream>>>(AO, wo, bo, out);
}